// Round 1
// baseline (840.650 us; speedup 1.0000x reference)
//
#include <hip/hip_runtime.h>
#include <cfloat>

// Problem constants (MoMEAdaptor): B=2,S=1024,H=2048,D=256,R=32,K=4,NDB=100000
#define B_   2
#define S_   1024
#define H_   2048
#define D_   256
#define R_   32
#define K_   4
#define NDB_ 100000

// Only queries (b, t<256) feed the attention (mask j<=i, i<1024 => j<1024 => t<256).
#define TSEL 256
#define NSEL (B_ * TSEL)          // 512 queries that need k-NN

// knn partial-GEMM tiling
#define NCHUNK     61             // db chunks
#define CHUNK_ROWS 1664           // 13 tiles * 128
#define TILES      13
#define NT         128            // db rows per tile
#define MT         64             // queries per block
#define KC         64             // K-chunk
#define LSTR       68             // padded LDS stride (bank-friendly, 16B aligned)

#define NEG_INF  (-3.0e38f)
#define IDX_MAX  0x7fffffff

// Workspace layout (bytes). Total 8 MB.
#define OFF_Q    0          // 2048*256 f32            (2 MB)
#define OFF_KN   0x200000   // 100000 f32              (400 KB)
#define OFF_PS   0x280000   // 512*61*4 f32            (~488 KB)
#define OFF_PI   0x300000   // 512*61*4 i32
#define OFF_IDX  0x380000   // 2048 i32 (final sorted top-4 per sel query)
#define OFF_KVT  0x400000   // kvT_key [2][256][1024] f32 (2 MB)
#define OFF_AO   0x600000   // attention out [2048][256] f32 (2 MB)

// sorted-insert of (score,idx) into descending top-4; ties -> lower index first
__device__ __forceinline__ void ins4(float sc, int n, float s[4], int id[4]) {
  if (sc > s[3] || (sc == s[3] && n < id[3])) {
    s[3] = sc; id[3] = n;
#pragma unroll
    for (int k = 3; k > 0; --k) {
      if (s[k] > s[k - 1] || (s[k] == s[k - 1] && id[k] < id[k - 1])) {
        float ts = s[k]; s[k] = s[k - 1]; s[k - 1] = ts;
        int ti = id[k]; id[k] = id[k - 1]; id[k - 1] = ti;
      }
    }
  }
}

// ---------------- q = (hidden @ wq_in) @ wq_out,  one block per token ----------------
__global__ __launch_bounds__(256) void k_compute_q(
    const float* __restrict__ hidden, const float* __restrict__ wq_in,
    const float* __restrict__ wq_out, float* __restrict__ q) {
  __shared__ float hrow[H_];
  __shared__ float part[8][R_];
  __shared__ float q1[R_];
  const int m = blockIdx.x;      // 0..2047
  const int t = threadIdx.x;
  const float* hp = hidden + (size_t)m * H_;
  ((float4*)hrow)[t]       = ((const float4*)hp)[t];
  ((float4*)hrow)[t + 256] = ((const float4*)hp)[t + 256];
  __syncthreads();
  const int r = t & 31, c = t >> 5;
  float p = 0.f;
#pragma unroll 4
  for (int e = c * 256; e < c * 256 + 256; ++e)
    p = fmaf(hrow[e], wq_in[(size_t)e * R_ + r], p);
  part[c][r] = p;
  __syncthreads();
  if (t < R_) {
    float s = 0.f;
#pragma unroll
    for (int cc = 0; cc < 8; ++cc) s += part[cc][t];
    q1[t] = s;
  }
  __syncthreads();
  float acc = 0.f;
#pragma unroll
  for (int rr = 0; rr < R_; ++rr) acc = fmaf(q1[rr], wq_out[rr * D_ + t], acc);
  q[(size_t)m * D_ + t] = acc;
}

// ---------------- kn[n] = |db_keys[n]|^2, one wave per row ----------------
__global__ __launch_bounds__(256) void k_kn(const float* __restrict__ dbk,
                                            float* __restrict__ kn) {
  const int w = threadIdx.x >> 6, l = threadIdx.x & 63;
  const int n = blockIdx.x * 4 + w;
  if (n >= NDB_) return;
  const float4 v = ((const float4*)(dbk + (size_t)n * D_))[l];
  float s = v.x * v.x + v.y * v.y + v.z * v.z + v.w * v.w;
#pragma unroll
  for (int off = 32; off; off >>= 1) s += __shfl_down(s, off);
  if (l == 0) kn[n] = s;
}

// ---------------- per-(query-block, db-chunk) partial top-4 ----------------
// score = 2*q.k - kn  (== -dist + qn, same ordering). fp32 GEMM, 64q x 128n tiles,
// per-thread 4q x 8n register tile. B tile split in two 64-wide LDS arrays so the
// two b-frag ds_read_b128 are 2-way (free) instead of 4-way conflicted.
__global__ __launch_bounds__(256) void k_knn_partial(
    const float* __restrict__ q, const float* __restrict__ dbk,
    const float* __restrict__ kn, float* __restrict__ pscore,
    int* __restrict__ pidx) {
  __shared__ float smem[3 * KC * LSTR];   // 52224 B
  float* sA  = smem;                      // q^T  [64 kk][64 q + pad]
  float* sB0 = smem + KC * LSTR;          // k^T  low-half frags
  float* sB1 = smem + 2 * KC * LSTR;      // k^T  high-half frags

  const int tid = threadIdx.x;
  const int tx = tid & 15, ty = tid >> 4;
  const int chunk = blockIdx.x, qb = blockIdx.y;

  // staging roles
  const int arq = tid >> 2;            // 0..63 query row
  const int aqd = (tid & 3) * 4;       // float offset within 64-chunk
  const int brk = tid >> 1;            // 0..127 db row
  const int bh  = tid & 1;
  const int bcol = ((brk >> 3) << 2) | (brk & 3);
  float* sBw = (brk & 4) ? sB1 : sB0;

  const int sq_a = qb * MT + arq;
  const float* qsrc = q + ((size_t)((sq_a >> 8) * S_ + (sq_a & 255))) * D_;

  float s4[4][4]; int i4[4][4];
#pragma unroll
  for (int a = 0; a < 4; ++a)
#pragma unroll
    for (int b = 0; b < 4; ++b) { s4[a][b] = NEG_INF; i4[a][b] = IDX_MAX; }

  const int row_base = chunk * CHUNK_ROWS;

  for (int tile = 0; tile < TILES; ++tile) {
    const int row0 = row_base + tile * NT;
    if (row0 >= NDB_) break;
    int krow = row0 + brk; if (krow >= NDB_) krow = NDB_ - 1;   // clamp; guarded at insert
    const float* ksrc = dbk + (size_t)krow * D_;

    float acc[4][8];
#pragma unroll
    for (int a = 0; a < 4; ++a)
#pragma unroll
      for (int b = 0; b < 8; ++b) acc[a][b] = 0.f;

    for (int kc = 0; kc < 4; ++kc) {
      __syncthreads();
#pragma unroll
      for (int p = 0; p < 4; ++p) {            // stage A (transpose)
        const int kkl = p * 16 + aqd;
        const float4 v = *(const float4*)(qsrc + kc * KC + kkl);
        sA[(kkl + 0) * LSTR + arq] = v.x;
        sA[(kkl + 1) * LSTR + arq] = v.y;
        sA[(kkl + 2) * LSTR + arq] = v.z;
        sA[(kkl + 3) * LSTR + arq] = v.w;
      }
#pragma unroll
      for (int p = 0; p < 8; ++p) {            // stage B (transpose, split halves)
        const int kkl = bh * 32 + p * 4;
        const float4 v = *(const float4*)(ksrc + kc * KC + kkl);
        sBw[(kkl + 0) * LSTR + bcol] = v.x;
        sBw[(kkl + 1) * LSTR + bcol] = v.y;
        sBw[(kkl + 2) * LSTR + bcol] = v.z;
        sBw[(kkl + 3) * LSTR + bcol] = v.w;
      }
      __syncthreads();
#pragma unroll 4
      for (int kk = 0; kk < KC; ++kk) {
        const float4 a  = *(const float4*)&sA [kk * LSTR + ty * 4];
        const float4 b0 = *(const float4*)&sB0[kk * LSTR + tx * 4];
        const float4 b1 = *(const float4*)&sB1[kk * LSTR + tx * 4];
        const float av[4] = {a.x, a.y, a.z, a.w};
        const float bv[8] = {b0.x, b0.y, b0.z, b0.w, b1.x, b1.y, b1.z, b1.w};
#pragma unroll
        for (int qi = 0; qi < 4; ++qi)
#pragma unroll
          for (int nj = 0; nj < 8; ++nj)
            acc[qi][nj] = fmaf(av[qi], bv[nj], acc[qi][nj]);
      }
    }
    // epilogue: candidates (n ascending within thread -> tie order preserved)
#pragma unroll
    for (int nj = 0; nj < 8; ++nj) {
      const int n = row0 + tx * 8 + nj;
      if (n < NDB_) {
        const float knj = kn[n];
        ins4(2.f * acc[0][nj] - knj, n, s4[0], i4[0]);
        ins4(2.f * acc[1][nj] - knj, n, s4[1], i4[1]);
        ins4(2.f * acc[2][nj] - knj, n, s4[2], i4[2]);
        ins4(2.f * acc[3][nj] - knj, n, s4[3], i4[3]);
      }
    }
  }

  // block merge: 64 candidates per query -> top-4 for (query, chunk)
  __syncthreads();
  float* cs = smem;                     // [64][65]
  int*   ci = (int*)(smem + 64 * 65);
#pragma unroll
  for (int qi = 0; qi < 4; ++qi)
#pragma unroll
    for (int k = 0; k < 4; ++k) {
      cs[(ty * 4 + qi) * 65 + tx * 4 + k] = s4[qi][k];
      ci[(ty * 4 + qi) * 65 + tx * 4 + k] = i4[qi][k];
    }
  __syncthreads();
  if (tid < 64) {
    float fs[4]; int fi[4];
#pragma unroll
    for (int k = 0; k < 4; ++k) { fs[k] = NEG_INF; fi[k] = IDX_MAX; }
    for (int c = 0; c < 64; ++c)
      ins4(cs[tid * 65 + c], ci[tid * 65 + c], fs, fi);
    const int sq = qb * MT + tid;
    float* po = pscore + ((size_t)sq * NCHUNK + chunk) * 4;
    int*   io = pidx   + ((size_t)sq * NCHUNK + chunk) * 4;
#pragma unroll
    for (int k = 0; k < 4; ++k) { po[k] = fs[k]; io[k] = fi[k]; }
  }
}

// ---------------- merge 61*4 chunk candidates -> sorted global top-4 ----------------
__global__ __launch_bounds__(64) void k_knn_merge(const float* __restrict__ pscore,
                                                  const int* __restrict__ pidx,
                                                  int* __restrict__ knn_idx) {
  const int sq = blockIdx.x, l = threadIdx.x;
  float s4[4]; int i4[4];
#pragma unroll
  for (int k = 0; k < 4; ++k) { s4[k] = NEG_INF; i4[k] = IDX_MAX; }
  for (int c = l; c < NCHUNK * 4; c += 64)
    ins4(pscore[(size_t)sq * NCHUNK * 4 + c], pidx[(size_t)sq * NCHUNK * 4 + c], s4, i4);
#pragma unroll
  for (int r = 0; r < 4; ++r) {
    float s = s4[0]; int i = i4[0];
#pragma unroll
    for (int off = 32; off; off >>= 1) {
      float so = __shfl_down(s, off); int io = __shfl_down(i, off);
      if (so > s || (so == s && io < i)) { s = so; i = io; }
    }
    const float sw = __shfl(s, 0); const int iw = __shfl(i, 0);
    if (l == 0) knn_idx[sq * 4 + r] = iw;
    if (s4[0] == sw && i4[0] == iw) {         // pop my head (db idx unique)
      s4[0] = s4[1]; i4[0] = i4[1];
      s4[1] = s4[2]; i4[1] = i4[2];
      s4[2] = s4[3]; i4[2] = i4[3];
      s4[3] = NEG_INF; i4[3] = IDX_MAX;
    }
  }
}

// ---------------- gather keys transposed: kvT[b][d][j] ----------------
__global__ __launch_bounds__(256) void k_gather(const float* __restrict__ dbk,
                                                const int* __restrict__ knn_idx,
                                                float* __restrict__ kvT) {
  const int b = blockIdx.x >> 6, j0 = (blockIdx.x & 63) * 16;
  const int w = threadIdx.x >> 6, l = threadIdx.x & 63;
  float* dst = kvT + (size_t)b * D_ * 1024;
  for (int jj = w; jj < 16; jj += 4) {
    const int j = j0 + jj;
    const int row = knn_idx[b * 1024 + j];
    const float4 v = ((const float4*)(dbk + (size_t)row * D_))[l];
    dst[(4 * l + 0) * 1024 + j] = v.x;
    dst[(4 * l + 1) * 1024 + j] = v.y;
    dst[(4 * l + 2) * 1024 + j] = v.z;
    dst[(4 * l + 3) * 1024 + j] = v.w;
  }
}

// ---------------- attention: one block per (b, i) ----------------
__global__ __launch_bounds__(256) void k_attn(const float* __restrict__ qarr,
                                              const float* __restrict__ kvT,
                                              const int* __restrict__ knn_idx,
                                              const float* __restrict__ dbv,
                                              float* __restrict__ attout) {
  __shared__ float qrow[D_];
  __shared__ float attw[1024];
  __shared__ int   jrow[1024];
  __shared__ float red1[4], red2[4];
  const int b = blockIdx.x >> 10, i = blockIdx.x & 1023;
  const int t = threadIdx.x;
  const int nk = i + 1;
  qrow[t] = qarr[((size_t)b * S_ + i) * D_ + t];
  for (int j = t; j < 1024; j += 256) jrow[j] = knn_idx[b * 1024 + j];
  __syncthreads();
  const int cmax = (nk + 255) >> 8;
  const float scale = 0.0625f;
  float sc[4]; float mloc = NEG_INF;
#pragma unroll
  for (int c = 0; c < 4; ++c) {
    sc[c] = NEG_INF;
    if (c < cmax) {
      const int j = c * 256 + t;
      float a = 0.f;
      const float* kp = kvT + (size_t)b * D_ * 1024 + j;
#pragma unroll 8
      for (int d = 0; d < D_; ++d) a = fmaf(qrow[d], kp[(size_t)d * 1024], a);
      if (j < nk) sc[c] = a * scale;
    }
    mloc = fmaxf(mloc, sc[c]);
  }
#pragma unroll
  for (int off = 32; off; off >>= 1) mloc = fmaxf(mloc, __shfl_down(mloc, off));
  if ((t & 63) == 0) red1[t >> 6] = mloc;
  __syncthreads();
  const float mmax = fmaxf(fmaxf(red1[0], red1[1]), fmaxf(red1[2], red1[3]));
  float sloc = 0.f; float pv[4];
#pragma unroll
  for (int c = 0; c < 4; ++c) {
    pv[c] = (sc[c] > NEG_INF * 0.5f) ? __expf(sc[c] - mmax) : 0.f;
    sloc += pv[c];
  }
#pragma unroll
  for (int off = 32; off; off >>= 1) sloc += __shfl_down(sloc, off);
  if ((t & 63) == 0) red2[t >> 6] = sloc;
  __syncthreads();
  const float inv = 1.f / (red2[0] + red2[1] + red2[2] + red2[3]);
#pragma unroll
  for (int c = 0; c < 4; ++c)
    if (c < cmax) attw[c * 256 + t] = pv[c] * inv;
  __syncthreads();
  // PV: thread t owns output dim d = t
  float a0 = 0.f, a1 = 0.f, a2 = 0.f, a3 = 0.f;
  int j = 0;
  for (; j + 4 <= nk; j += 4) {
    a0 = fmaf(attw[j + 0], dbv[(size_t)jrow[j + 0] * D_ + t], a0);
    a1 = fmaf(attw[j + 1], dbv[(size_t)jrow[j + 1] * D_ + t], a1);
    a2 = fmaf(attw[j + 2], dbv[(size_t)jrow[j + 2] * D_ + t], a2);
    a3 = fmaf(attw[j + 3], dbv[(size_t)jrow[j + 3] * D_ + t], a3);
  }
  for (; j < nk; ++j) a0 = fmaf(attw[j], dbv[(size_t)jrow[j] * D_ + t], a0);
  attout[((size_t)b * S_ + i) * D_ + t] = (a0 + a1) + (a2 + a3);
}

// ---------------- y = (attout @ wv_in) @ wv_out, one block per token ----------------
__global__ __launch_bounds__(256) void k_out(const float* __restrict__ attout,
                                             const float* __restrict__ wv_in,
                                             const float* __restrict__ wv_out,
                                             float* __restrict__ y) {
  __shared__ float row[D_];
  __shared__ float part[8][R_];
  __shared__ float t32[R_];
  const int m = blockIdx.x, t = threadIdx.x;
  row[t] = attout[(size_t)m * D_ + t];
  __syncthreads();
  const int r = t & 31, c = t >> 5;
  float p = 0.f;
#pragma unroll
  for (int d = c * 32; d < c * 32 + 32; ++d)
    p = fmaf(row[d], wv_in[d * R_ + r], p);
  part[c][r] = p;
  __syncthreads();
  if (t < R_) {
    float s = 0.f;
#pragma unroll
    for (int cc = 0; cc < 8; ++cc) s += part[cc][t];
    t32[t] = s;
  }
  __syncthreads();
  for (int hh = t; hh < H_; hh += 256) {
    float a = 0.f;
#pragma unroll
    for (int rr = 0; rr < R_; ++rr) a = fmaf(t32[rr], wv_out[rr * H_ + hh], a);
    y[(size_t)m * H_ + hh] = a;
  }
}

extern "C" void kernel_launch(void* const* d_in, const int* in_sizes, int n_in,
                              void* d_out, int out_size, void* d_ws, size_t ws_size,
                              hipStream_t stream) {
  const float* hidden  = (const float*)d_in[0];
  const float* db_keys = (const float*)d_in[1];
  const float* db_vals = (const float*)d_in[2];
  const float* wq_in   = (const float*)d_in[3];
  const float* wq_out  = (const float*)d_in[4];
  const float* wv_in   = (const float*)d_in[5];
  const float* wv_out  = (const float*)d_in[6];
  float* out = (float*)d_out;

  char* ws = (char*)d_ws;                 // needs 8 MB
  float* q       = (float*)(ws + OFF_Q);
  float* kn      = (float*)(ws + OFF_KN);
  float* ps      = (float*)(ws + OFF_PS);
  int*   pi      = (int*)  (ws + OFF_PI);
  int*   idx     = (int*)  (ws + OFF_IDX);
  float* kvT     = (float*)(ws + OFF_KVT);
  float* attout  = (float*)(ws + OFF_AO);

  k_compute_q<<<B_ * S_, 256, 0, stream>>>(hidden, wq_in, wq_out, q);
  k_kn<<<(NDB_ + 3) / 4, 256, 0, stream>>>(db_keys, kn);
  k_knn_partial<<<dim3(NCHUNK, 8), 256, 0, stream>>>(q, db_keys, kn, ps, pi);
  k_knn_merge<<<NSEL, 64, 0, stream>>>(ps, pi, idx);
  k_gather<<<2 * 64, 256, 0, stream>>>(db_keys, idx, kvT);
  k_attn<<<B_ * S_, 256, 0, stream>>>(q, kvT, idx, db_vals, attout);
  k_out<<<B_ * S_, 256, 0, stream>>>(attout, wv_in, wv_out, out);
}

// Round 2
// 550.608 us; speedup vs baseline: 1.5268x; 1.5268x over previous
//
#include <hip/hip_runtime.h>
#include <cfloat>

// Problem constants (MoMEAdaptor): B=2,S=1024,H=2048,D=256,R=32,K=4,NDB=100000
#define B_   2
#define S_   1024
#define H_   2048
#define D_   256
#define R_   32
#define K_   4
#define NDB_ 100000

// Only queries (b, t<256) feed the attention (mask j<=i => j<1024 => t<256).
#define TSEL 256
#define NSEL (B_ * TSEL)          // 512 queries that need k-NN

// knn tiling (shared by fp32 fallback and MFMA path)
#define NCHUNK     61             // db chunks
#define CHUNK_ROWS 1664           // 13 tiles * 128
#define TILES      13
#define NT         128            // db rows per tile
#define MT         64             // queries per block
#define KC         64             // fallback K-chunk
#define LSTR       68             // fallback padded LDS stride

#define NEG_INF  (-3.0e38f)
#define IDX_MAX  0x7fffffff

// Workspace layout (bytes).
#define OFF_Q     0          // 2048*256 f32            (2 MB)
#define OFF_KN    0x200000   // 100000 f32              (400 KB)
#define OFF_PS    0x280000   // 512*61*4 f32
#define OFF_PI    0x300000   // 512*61*4 i32
#define OFF_IDX   0x380000   // 2048 i32 (final sorted top-4 per sel query)
#define OFF_CAND  0x3A0000   // 512*16 i32 candidates   (32 KB)
#define OFF_KVT   0x400000   // kvT_key [2][256][1024] f32 (2 MB)
#define OFF_AO    0x600000   // attention out [2048][256] f32 (2 MB)
#define OFF_DBK16 0x800000   // bf16 db copy 100000*256*2 = 51.2 MB

typedef unsigned short ushort_t;
typedef unsigned int   uint_t;
typedef __attribute__((ext_vector_type(8)))  __bf16 bf16x8;
typedef __attribute__((ext_vector_type(16))) float  f32x16;

// sorted-insert of (score,idx) into descending top-4; ties -> lower index first
__device__ __forceinline__ void ins4(float sc, int n, float s[4], int id[4]) {
  if (sc > s[3] || (sc == s[3] && n < id[3])) {
    s[3] = sc; id[3] = n;
#pragma unroll
    for (int k = 3; k > 0; --k) {
      if (s[k] > s[k - 1] || (s[k] == s[k - 1] && id[k] < id[k - 1])) {
        float ts = s[k]; s[k] = s[k - 1]; s[k - 1] = ts;
        int ti = id[k]; id[k] = id[k - 1]; id[k - 1] = ti;
      }
    }
  }
}

__device__ __forceinline__ uint_t bfpack(float a, float b) {   // 2x fp32 -> packed bf16 (RNE)
  uint_t ua = __float_as_uint(a), ub = __float_as_uint(b);
  ua = (ua + 0x7fffu + ((ua >> 16) & 1u)) >> 16;
  ub = (ub + 0x7fffu + ((ub >> 16) & 1u)) >> 16;
  return ua | (ub << 16);
}

// ---------------- q = (hidden @ wq_in) @ wq_out,  one block per token ----------------
__global__ __launch_bounds__(256) void k_compute_q(
    const float* __restrict__ hidden, const float* __restrict__ wq_in,
    const float* __restrict__ wq_out, float* __restrict__ q) {
  __shared__ float hrow[H_];
  __shared__ float part[8][R_];
  __shared__ float q1[R_];
  const int m = blockIdx.x;
  const int t = threadIdx.x;
  const float* hp = hidden + (size_t)m * H_;
  ((float4*)hrow)[t]       = ((const float4*)hp)[t];
  ((float4*)hrow)[t + 256] = ((const float4*)hp)[t + 256];
  __syncthreads();
  const int r = t & 31, c = t >> 5;
  float p = 0.f;
#pragma unroll 4
  for (int e = c * 256; e < c * 256 + 256; ++e)
    p = fmaf(hrow[e], wq_in[(size_t)e * R_ + r], p);
  part[c][r] = p;
  __syncthreads();
  if (t < R_) {
    float s = 0.f;
#pragma unroll
    for (int cc = 0; cc < 8; ++cc) s += part[cc][t];
    q1[t] = s;
  }
  __syncthreads();
  float acc = 0.f;
#pragma unroll
  for (int rr = 0; rr < R_; ++rr) acc = fmaf(q1[rr], wq_out[rr * D_ + t], acc);
  q[(size_t)m * D_ + t] = acc;
}

// ---------------- kn[n] = |db_keys[n]|^2 (+ fused bf16 conversion) ----------------
__global__ __launch_bounds__(256) void k_kn_cvt(const float* __restrict__ dbk,
                                               float* __restrict__ kn,
                                               ushort_t* __restrict__ dbk16) {
  const int w = threadIdx.x >> 6, l = threadIdx.x & 63;
  const int n = blockIdx.x * 4 + w;
  if (n >= NDB_) return;
  const float4 v = ((const float4*)(dbk + (size_t)n * D_))[l];
  uint2 p; p.x = bfpack(v.x, v.y); p.y = bfpack(v.z, v.w);
  ((uint2*)(dbk16 + (size_t)n * D_))[l] = p;
  float s = v.x * v.x + v.y * v.y + v.z * v.z + v.w * v.w;
#pragma unroll
  for (int off = 32; off; off >>= 1) s += __shfl_down(s, off);
  if (l == 0) kn[n] = s;
}

// plain kn (fallback path, no bf16 copy)
__global__ __launch_bounds__(256) void k_kn(const float* __restrict__ dbk,
                                            float* __restrict__ kn) {
  const int w = threadIdx.x >> 6, l = threadIdx.x & 63;
  const int n = blockIdx.x * 4 + w;
  if (n >= NDB_) return;
  const float4 v = ((const float4*)(dbk + (size_t)n * D_))[l];
  float s = v.x * v.x + v.y * v.y + v.z * v.z + v.w * v.w;
#pragma unroll
  for (int off = 32; off; off >>= 1) s += __shfl_down(s, off);
  if (l == 0) kn[n] = s;
}

// ---------------- MFMA knn: per-(query-block, db-chunk) partial top-4 ----------------
// approx score = 2*(q.k)_bf16 - kn_fp32. Block: 64q x 128n tile, K=256 in two halves.
// A (q bf16, 64x256) resident in LDS with XOR chunk swizzle; B staged per k-half via
// global_load_lds width=16 (swizzle folded into the global-side gather, LDS side is
// lane-contiguous as required). Scores round-trip through the B buffer (overlay).
__global__ __launch_bounds__(256, 2) void k_knn_mfma(
    const float* __restrict__ q, const ushort_t* __restrict__ dbk16,
    const float* __restrict__ kn, float* __restrict__ pscore,
    int* __restrict__ pidx) {
  __shared__ __align__(16) char smem[65536];
  ushort_t* sA = (ushort_t*)smem;            // 64 rows x 32 chunks x 16B = 32768
  ushort_t* sB = (ushort_t*)(smem + 32768);  // 128 rows x 16 chunks x 16B = 32768
  float*    sS = (float*)(smem + 32768);     // scores [64 m][128 n] overlay on B

  const int tid = threadIdx.x;
  const int wv = tid >> 6, ln = tid & 63;
  const int lm = ln & 31, lh = ln >> 5;
  const int tx = tid & 15, ty = tid >> 4;
  const int chunk = blockIdx.x, qb = blockIdx.y;
  const int row_base = chunk * CHUNK_ROWS;

  // ---- stage A once: 64 selected q rows -> bf16, swizzled chunks ----
  {
    const int m = tid & 63, cg = tid >> 6;
    const int sq = qb * MT + m;
    const float* qp = q + ((size_t)((sq >> 8) * S_ + (sq & 255))) * D_;
#pragma unroll
    for (int cc = 0; cc < 8; ++cc) {
      const int c = cg * 8 + cc;
      const float4 v0 = *(const float4*)(qp + c * 8);
      const float4 v1 = *(const float4*)(qp + c * 8 + 4);
      uint4 pk;
      pk.x = bfpack(v0.x, v0.y); pk.y = bfpack(v0.z, v0.w);
      pk.z = bfpack(v1.x, v1.y); pk.w = bfpack(v1.z, v1.w);
      *(uint4*)&sA[(m * 32 + (c ^ (m & 7))) * 8] = pk;
    }
  }

  float s4[4][4]; int i4[4][4];
#pragma unroll
  for (int a = 0; a < 4; ++a)
#pragma unroll
    for (int b = 0; b < 4; ++b) { s4[a][b] = NEG_INF; i4[a][b] = IDX_MAX; }

  for (int tile = 0; tile < TILES; ++tile) {
    const int row0 = row_base + tile * NT;
    if (row0 >= NDB_) break;

    f32x16 acc0, acc1;
#pragma unroll
    for (int r = 0; r < 16; ++r) { acc0[r] = 0.f; acc1[r] = 0.f; }

    for (int kh = 0; kh < 2; ++kh) {
      __syncthreads();    // prev consumers of sB/sS done
      // ---- stage B half: wave wv stages rows [wv*32, wv*32+32) ----
      {
        const int n_in = ln >> 4;          // row within 4-row instr group
        const int p    = ln & 15;          // stored chunk position
#pragma unroll
        for (int i = 0; i < 8; ++i) {
          const int nloc = wv * 32 + i * 4 + n_in;
          int krow = row0 + nloc; if (krow >= NDB_) krow = NDB_ - 1;
          const int c = p ^ (nloc & 7);    // global chunk within half
          const ushort_t* gp = dbk16 + (size_t)krow * D_ + (kh * 16 + c) * 8;
          ushort_t* lp = sB + (size_t)(wv * 32 + i * 4) * 128;  // wave-uniform base
          __builtin_amdgcn_global_load_lds(
              (const __attribute__((address_space(1))) void*)gp,
              (__attribute__((address_space(3))) void*)lp, 16, 0, 0);
        }
      }
      __syncthreads();
      // ---- MFMA over this k-half: 8 steps of K=16 ----
      const int nB = wv * 32 + lm;
      const int bswz = nB & 7;
#pragma unroll
      for (int ks = 0; ks < 8; ++ks) {
        const int cA = kh * 16 + ks * 2 + lh;
        const bf16x8 a0 = *(const bf16x8*)&sA[(lm * 32 + (cA ^ (lm & 7))) * 8];
        const bf16x8 a1 = *(const bf16x8*)&sA[((32 + lm) * 32 + (cA ^ (lm & 7))) * 8];
        const bf16x8 bb = *(const bf16x8*)&sB[(nB * 16 + ((ks * 2 + lh) ^ bswz)) * 8];
        acc0 = __builtin_amdgcn_mfma_f32_32x32x16_bf16(a0, bb, acc0, 0, 0, 0);
        acc1 = __builtin_amdgcn_mfma_f32_32x32x16_bf16(a1, bb, acc1, 0, 0, 0);
      }
    }
    __syncthreads();     // B reads done -> safe to overlay scores
    // ---- write C frags to LDS: sS[m][n], 2-way-max on writes ----
    {
      const int n = wv * 32 + lm;
#pragma unroll
      for (int r = 0; r < 16; ++r) {
        const int mrow = (r & 3) + 8 * (r >> 2) + 4 * lh;
        sS[mrow * 128 + n]        = acc0[r];
        sS[(32 + mrow) * 128 + n] = acc1[r];
      }
    }
    __syncthreads();
    // ---- select: thread = 8 n cols x 4 q rows, running top-4 ----
    {
      float knv[8]; int nok[8];
#pragma unroll
      for (int j = 0; j < 8; ++j) {
        const int n = row0 + tx * 8 + j;
        nok[j] = (n < NDB_);
        knv[j] = nok[j] ? kn[n] : 0.f;
      }
#pragma unroll
      for (int qi = 0; qi < 4; ++qi) {
        const int m = ty * 4 + qi;
        const float4 v0 = *(const float4*)&sS[m * 128 + tx * 8];
        const float4 v1 = *(const float4*)&sS[m * 128 + tx * 8 + 4];
        const float sv[8] = {v0.x, v0.y, v0.z, v0.w, v1.x, v1.y, v1.z, v1.w};
#pragma unroll
        for (int j = 0; j < 8; ++j)
          if (nok[j]) ins4(2.f * sv[j] - knv[j], row0 + tx * 8 + j, s4[qi], i4[qi]);
      }
    }
  }

  // ---- block merge: 64 candidate-sets of 4 per query -> top-4 for (query, chunk) ----
  __syncthreads();
  float* cs = (float*)smem;
  int*   ci = (int*)(smem + 64 * 65 * 4);
#pragma unroll
  for (int qi = 0; qi < 4; ++qi)
#pragma unroll
    for (int k = 0; k < 4; ++k) {
      cs[(ty * 4 + qi) * 65 + tx * 4 + k] = s4[qi][k];
      ci[(ty * 4 + qi) * 65 + tx * 4 + k] = i4[qi][k];
    }
  __syncthreads();
  if (tid < 64) {
    float fs[4]; int fi[4];
#pragma unroll
    for (int k = 0; k < 4; ++k) { fs[k] = NEG_INF; fi[k] = IDX_MAX; }
    for (int c = 0; c < 64; ++c)
      ins4(cs[tid * 65 + c], ci[tid * 65 + c], fs, fi);
    const int sq = qb * MT + tid;
    float* po = pscore + ((size_t)sq * NCHUNK + chunk) * 4;
    int*   io = pidx   + ((size_t)sq * NCHUNK + chunk) * 4;
#pragma unroll
    for (int k = 0; k < 4; ++k) { po[k] = fs[k]; io[k] = fi[k]; }
  }
}

// ---------------- fp32 fallback knn (round-1 kernel, used if ws too small) ----------------
__global__ __launch_bounds__(256) void k_knn_partial(
    const float* __restrict__ q, const float* __restrict__ dbk,
    const float* __restrict__ kn, float* __restrict__ pscore,
    int* __restrict__ pidx) {
  __shared__ float smem[3 * KC * LSTR];
  float* sA  = smem;
  float* sB0 = smem + KC * LSTR;
  float* sB1 = smem + 2 * KC * LSTR;
  const int tid = threadIdx.x;
  const int tx = tid & 15, ty = tid >> 4;
  const int chunk = blockIdx.x, qb = blockIdx.y;
  const int arq = tid >> 2;
  const int aqd = (tid & 3) * 4;
  const int brk = tid >> 1;
  const int bh  = tid & 1;
  const int bcol = ((brk >> 3) << 2) | (brk & 3);
  float* sBw = (brk & 4) ? sB1 : sB0;
  const int sq_a = qb * MT + arq;
  const float* qsrc = q + ((size_t)((sq_a >> 8) * S_ + (sq_a & 255))) * D_;
  float s4[4][4]; int i4[4][4];
#pragma unroll
  for (int a = 0; a < 4; ++a)
#pragma unroll
    for (int b = 0; b < 4; ++b) { s4[a][b] = NEG_INF; i4[a][b] = IDX_MAX; }
  const int row_base = chunk * CHUNK_ROWS;
  for (int tile = 0; tile < TILES; ++tile) {
    const int row0 = row_base + tile * NT;
    if (row0 >= NDB_) break;
    int krow = row0 + brk; if (krow >= NDB_) krow = NDB_ - 1;
    const float* ksrc = dbk + (size_t)krow * D_;
    float acc[4][8];
#pragma unroll
    for (int a = 0; a < 4; ++a)
#pragma unroll
      for (int b = 0; b < 8; ++b) acc[a][b] = 0.f;
    for (int kc = 0; kc < 4; ++kc) {
      __syncthreads();
#pragma unroll
      for (int p = 0; p < 4; ++p) {
        const int kkl = p * 16 + aqd;
        const float4 v = *(const float4*)(qsrc + kc * KC + kkl);
        sA[(kkl + 0) * LSTR + arq] = v.x;
        sA[(kkl + 1) * LSTR + arq] = v.y;
        sA[(kkl + 2) * LSTR + arq] = v.z;
        sA[(kkl + 3) * LSTR + arq] = v.w;
      }
#pragma unroll
      for (int p = 0; p < 8; ++p) {
        const int kkl = bh * 32 + p * 4;
        const float4 v = *(const float4*)(ksrc + kc * KC + kkl);
        sBw[(kkl + 0) * LSTR + bcol] = v.x;
        sBw[(kkl + 1) * LSTR + bcol] = v.y;
        sBw[(kkl + 2) * LSTR + bcol] = v.z;
        sBw[(kkl + 3) * LSTR + bcol] = v.w;
      }
      __syncthreads();
#pragma unroll 4
      for (int kk = 0; kk < KC; ++kk) {
        const float4 a  = *(const float4*)&sA [kk * LSTR + ty * 4];
        const float4 b0 = *(const float4*)&sB0[kk * LSTR + tx * 4];
        const float4 b1 = *(const float4*)&sB1[kk * LSTR + tx * 4];
        const float av[4] = {a.x, a.y, a.z, a.w};
        const float bv[8] = {b0.x, b0.y, b0.z, b0.w, b1.x, b1.y, b1.z, b1.w};
#pragma unroll
        for (int qi = 0; qi < 4; ++qi)
#pragma unroll
          for (int nj = 0; nj < 8; ++nj)
            acc[qi][nj] = fmaf(av[qi], bv[nj], acc[qi][nj]);
      }
    }
#pragma unroll
    for (int nj = 0; nj < 8; ++nj) {
      const int n = row0 + tx * 8 + nj;
      if (n < NDB_) {
        const float knj = kn[n];
        ins4(2.f * acc[0][nj] - knj, n, s4[0], i4[0]);
        ins4(2.f * acc[1][nj] - knj, n, s4[1], i4[1]);
        ins4(2.f * acc[2][nj] - knj, n, s4[2], i4[2]);
        ins4(2.f * acc[3][nj] - knj, n, s4[3], i4[3]);
      }
    }
  }
  __syncthreads();
  float* cs = smem;
  int*   ci = (int*)(smem + 64 * 65);
#pragma unroll
  for (int qi = 0; qi < 4; ++qi)
#pragma unroll
    for (int k = 0; k < 4; ++k) {
      cs[(ty * 4 + qi) * 65 + tx * 4 + k] = s4[qi][k];
      ci[(ty * 4 + qi) * 65 + tx * 4 + k] = i4[qi][k];
    }
  __syncthreads();
  if (tid < 64) {
    float fs[4]; int fi[4];
#pragma unroll
    for (int k = 0; k < 4; ++k) { fs[k] = NEG_INF; fi[k] = IDX_MAX; }
    for (int c = 0; c < 64; ++c)
      ins4(cs[tid * 65 + c], ci[tid * 65 + c], fs, fi);
    const int sq = qb * MT + tid;
    float* po = pscore + ((size_t)sq * NCHUNK + chunk) * 4;
    int*   io = pidx   + ((size_t)sq * NCHUNK + chunk) * 4;
#pragma unroll
    for (int k = 0; k < 4; ++k) { po[k] = fs[k]; io[k] = fi[k]; }
  }
}

// ---------------- merge chunk candidates -> sorted global top-R ----------------
template <int RANKS>
__device__ __forceinline__ void merge_top(const float* __restrict__ pscore,
                                          const int* __restrict__ pidx,
                                          int* __restrict__ outp) {
  const int sq = blockIdx.x, l = threadIdx.x;
  float s4[4]; int i4[4];
#pragma unroll
  for (int k = 0; k < 4; ++k) { s4[k] = NEG_INF; i4[k] = IDX_MAX; }
  for (int c = l; c < NCHUNK * 4; c += 64)
    ins4(pscore[(size_t)sq * NCHUNK * 4 + c], pidx[(size_t)sq * NCHUNK * 4 + c], s4, i4);
#pragma unroll
  for (int r = 0; r < RANKS; ++r) {
    float s = s4[0]; int i = i4[0];
#pragma unroll
    for (int off = 32; off; off >>= 1) {
      float so = __shfl_down(s, off); int io = __shfl_down(i, off);
      if (so > s || (so == s && io < i)) { s = so; i = io; }
    }
    const float sw = __shfl(s, 0); const int iw = __shfl(i, 0);
    if (l == 0) outp[sq * RANKS + r] = iw;
    if (s4[0] == sw && i4[0] == iw) {
      s4[0] = s4[1]; i4[0] = i4[1];
      s4[1] = s4[2]; i4[1] = i4[2];
      s4[2] = s4[3]; i4[2] = i4[3];
      s4[3] = NEG_INF; i4[3] = IDX_MAX;
    }
  }
}

__global__ __launch_bounds__(64) void k_knn_merge4(const float* __restrict__ ps,
                                                   const int* __restrict__ pi,
                                                   int* __restrict__ knn_idx) {
  merge_top<4>(ps, pi, knn_idx);
}
__global__ __launch_bounds__(64) void k_knn_merge16(const float* __restrict__ ps,
                                                    const int* __restrict__ pi,
                                                    int* __restrict__ cand) {
  merge_top<16>(ps, pi, cand);
}

// ---------------- exact fp32 rescore of 16 candidates -> final sorted top-4 ----------------
__global__ __launch_bounds__(256) void k_rescore(const float* __restrict__ q,
                                                 const float* __restrict__ dbk,
                                                 const float* __restrict__ kn,
                                                 const int* __restrict__ cand,
                                                 int* __restrict__ knn_idx) {
  __shared__ float scs[16];
  __shared__ int   sci[16];
  const int sq = blockIdx.x, wv = threadIdx.x >> 6, l = threadIdx.x & 63;
  const float* qp = q + ((size_t)((sq >> 8) * S_ + (sq & 255))) * D_;
  const float4 qv = ((const float4*)qp)[l];
  for (int cc = wv; cc < 16; cc += 4) {
    const int n = cand[sq * 16 + cc];
    const float4 kv = ((const float4*)(dbk + (size_t)n * D_))[l];
    float s = qv.x * kv.x + qv.y * kv.y + qv.z * kv.z + qv.w * kv.w;
#pragma unroll
    for (int off = 32; off; off >>= 1) s += __shfl_down(s, off);
    if (l == 0) { scs[cc] = 2.f * s - kn[n]; sci[cc] = n; }
  }
  __syncthreads();
  if (threadIdx.x == 0) {
    float s4[4]; int i4[4];
#pragma unroll
    for (int k = 0; k < 4; ++k) { s4[k] = NEG_INF; i4[k] = IDX_MAX; }
#pragma unroll
    for (int c = 0; c < 16; ++c) ins4(scs[c], sci[c], s4, i4);
#pragma unroll
    for (int k = 0; k < 4; ++k) knn_idx[sq * 4 + k] = i4[k];
  }
}

// ---------------- gather keys transposed: kvT[b][d][j] ----------------
__global__ __launch_bounds__(256) void k_gather(const float* __restrict__ dbk,
                                                const int* __restrict__ knn_idx,
                                                float* __restrict__ kvT) {
  const int b = blockIdx.x >> 6, j0 = (blockIdx.x & 63) * 16;
  const int w = threadIdx.x >> 6, l = threadIdx.x & 63;
  float* dst = kvT + (size_t)b * D_ * 1024;
  for (int jj = w; jj < 16; jj += 4) {
    const int j = j0 + jj;
    const int row = knn_idx[b * 1024 + j];
    const float4 v = ((const float4*)(dbk + (size_t)row * D_))[l];
    dst[(4 * l + 0) * 1024 + j] = v.x;
    dst[(4 * l + 1) * 1024 + j] = v.y;
    dst[(4 * l + 2) * 1024 + j] = v.z;
    dst[(4 * l + 3) * 1024 + j] = v.w;
  }
}

// ---------------- attention: one block per (b, i) ----------------
__global__ __launch_bounds__(256) void k_attn(const float* __restrict__ qarr,
                                              const float* __restrict__ kvT,
                                              const int* __restrict__ knn_idx,
                                              const float* __restrict__ dbv,
                                              float* __restrict__ attout) {
  __shared__ float qrow[D_];
  __shared__ float attw[1024];
  __shared__ int   jrow[1024];
  __shared__ float red1[4], red2[4];
  const int b = blockIdx.x >> 10, i = blockIdx.x & 1023;
  const int t = threadIdx.x;
  const int nk = i + 1;
  qrow[t] = qarr[((size_t)b * S_ + i) * D_ + t];
  for (int j = t; j < 1024; j += 256) jrow[j] = knn_idx[b * 1024 + j];
  __syncthreads();
  const int cmax = (nk + 255) >> 8;
  const float scale = 0.0625f;
  float sc[4]; float mloc = NEG_INF;
#pragma unroll
  for (int c = 0; c < 4; ++c) {
    sc[c] = NEG_INF;
    if (c < cmax) {
      const int j = c * 256 + t;
      float a = 0.f;
      const float* kp = kvT + (size_t)b * D_ * 1024 + j;
#pragma unroll 8
      for (int d = 0; d < D_; ++d) a = fmaf(qrow[d], kp[(size_t)d * 1024], a);
      if (j < nk) sc[c] = a * scale;
    }
    mloc = fmaxf(mloc, sc[c]);
  }
#pragma unroll
  for (int off = 32; off; off >>= 1) mloc = fmaxf(mloc, __shfl_down(mloc, off));
  if ((t & 63) == 0) red1[t >> 6] = mloc;
  __syncthreads();
  const float mmax = fmaxf(fmaxf(red1[0], red1[1]), fmaxf(red1[2], red1[3]));
  float sloc = 0.f; float pv[4];
#pragma unroll
  for (int c = 0; c < 4; ++c) {
    pv[c] = (sc[c] > NEG_INF * 0.5f) ? __expf(sc[c] - mmax) : 0.f;
    sloc += pv[c];
  }
#pragma unroll
  for (int off = 32; off; off >>= 1) sloc += __shfl_down(sloc, off);
  if ((t & 63) == 0) red2[t >> 6] = sloc;
  __syncthreads();
  const float inv = 1.f / (red2[0] + red2[1] + red2[2] + red2[3]);
#pragma unroll
  for (int c = 0; c < 4; ++c)
    if (c < cmax) attw[c * 256 + t] = pv[c] * inv;
  __syncthreads();
  float a0 = 0.f, a1 = 0.f, a2 = 0.f, a3 = 0.f;
  int j = 0;
  for (; j + 4 <= nk; j += 4) {
    a0 = fmaf(attw[j + 0], dbv[(size_t)jrow[j + 0] * D_ + t], a0);
    a1 = fmaf(attw[j + 1], dbv[(size_t)jrow[j + 1] * D_ + t], a1);
    a2 = fmaf(attw[j + 2], dbv[(size_t)jrow[j + 2] * D_ + t], a2);
    a3 = fmaf(attw[j + 3], dbv[(size_t)jrow[j + 3] * D_ + t], a3);
  }
  for (; j < nk; ++j) a0 = fmaf(attw[j], dbv[(size_t)jrow[j] * D_ + t], a0);
  attout[((size_t)b * S_ + i) * D_ + t] = (a0 + a1) + (a2 + a3);
}

// ---------------- y = (attout @ wv_in) @ wv_out, one block per token ----------------
__global__ __launch_bounds__(256) void k_out(const float* __restrict__ attout,
                                             const float* __restrict__ wv_in,
                                             const float* __restrict__ wv_out,
                                             float* __restrict__ y) {
  __shared__ float row[D_];
  __shared__ float part[8][R_];
  __shared__ float t32[R_];
  const int m = blockIdx.x, t = threadIdx.x;
  row[t] = attout[(size_t)m * D_ + t];
  __syncthreads();
  const int r = t & 31, c = t >> 5;
  float p = 0.f;
#pragma unroll
  for (int d = c * 32; d < c * 32 + 32; ++d)
    p = fmaf(row[d], wv_in[d * R_ + r], p);
  part[c][r] = p;
  __syncthreads();
  if (t < R_) {
    float s = 0.f;
#pragma unroll
    for (int cc = 0; cc < 8; ++cc) s += part[cc][t];
    t32[t] = s;
  }
  __syncthreads();
  for (int hh = t; hh < H_; hh += 256) {
    float a = 0.f;
#pragma unroll
    for (int rr = 0; rr < R_; ++rr) a = fmaf(t32[rr], wv_out[rr * H_ + hh], a);
    y[(size_t)m * H_ + hh] = a;
  }
}

extern "C" void kernel_launch(void* const* d_in, const int* in_sizes, int n_in,
                              void* d_out, int out_size, void* d_ws, size_t ws_size,
                              hipStream_t stream) {
  const float* hidden  = (const float*)d_in[0];
  const float* db_keys = (const float*)d_in[1];
  const float* db_vals = (const float*)d_in[2];
  const float* wq_in   = (const float*)d_in[3];
  const float* wq_out  = (const float*)d_in[4];
  const float* wv_in   = (const float*)d_in[5];
  const float* wv_out  = (const float*)d_in[6];
  float* out = (float*)d_out;

  char* ws = (char*)d_ws;
  float*    q      = (float*)(ws + OFF_Q);
  float*    kn     = (float*)(ws + OFF_KN);
  float*    ps     = (float*)(ws + OFF_PS);
  int*      pi     = (int*)  (ws + OFF_PI);
  int*      idx    = (int*)  (ws + OFF_IDX);
  int*      cand   = (int*)  (ws + OFF_CAND);
  float*    kvT    = (float*)(ws + OFF_KVT);
  float*    attout = (float*)(ws + OFF_AO);
  ushort_t* dbk16  = (ushort_t*)(ws + OFF_DBK16);

  const size_t need = (size_t)OFF_DBK16 + (size_t)NDB_ * D_ * 2;

  k_compute_q<<<B_ * S_, 256, 0, stream>>>(hidden, wq_in, wq_out, q);
  if (ws_size >= need) {
    // MFMA candidate path + exact fp32 rescore
    k_kn_cvt<<<(NDB_ + 3) / 4, 256, 0, stream>>>(db_keys, kn, dbk16);
    k_knn_mfma<<<dim3(NCHUNK, 8), 256, 0, stream>>>(q, dbk16, kn, ps, pi);
    k_knn_merge16<<<NSEL, 64, 0, stream>>>(ps, pi, cand);
    k_rescore<<<NSEL, 256, 0, stream>>>(q, db_keys, kn, cand, idx);
  } else {
    // fp32 fallback (round-1 path)
    k_kn<<<(NDB_ + 3) / 4, 256, 0, stream>>>(db_keys, kn);
    k_knn_partial<<<dim3(NCHUNK, 8), 256, 0, stream>>>(q, db_keys, kn, ps, pi);
    k_knn_merge4<<<NSEL, 64, 0, stream>>>(ps, pi, idx);
  }
  k_gather<<<2 * 64, 256, 0, stream>>>(db_keys, idx, kvT);
  k_attn<<<B_ * S_, 256, 0, stream>>>(q, kvT, idx, db_vals, attout);
  k_out<<<B_ * S_, 256, 0, stream>>>(attout, wv_in, wv_out, out);
}

// Round 4
// 544.369 us; speedup vs baseline: 1.5443x; 1.0115x over previous
//
#include <hip/hip_runtime.h>
#include <cfloat>

// Problem constants (MoMEAdaptor): B=2,S=1024,H=2048,D=256,R=32,K=4,NDB=100000
#define B_   2
#define S_   1024
#define H_   2048
#define D_   256
#define R_   32
#define K_   4
#define NDB_ 100000

// Only queries (b, t<256) feed the attention (mask j<=i => j<1024 => t<256).
#define TSEL 256
#define NSEL (B_ * TSEL)          // 512 queries that need k-NN

// knn tiling
#define NCHUNK     61             // db chunks
#define CHUNK_ROWS 1664           // 13 tiles * 128
#define TILES      13
#define NT         128            // db rows per tile
#define MT         64             // queries per block
#define KC         64             // fallback K-chunk
#define LSTR       68             // fallback padded LDS stride

#define NEG_INF  (-3.0e38f)
#define IDX_MAX  0x7fffffff

// Workspace layout (bytes). need = 0xA00000 + 51.2MB
#define OFF_Q     0          // 2048*256 f32            (2 MB)
#define OFF_KN    0x200000   // 100000 f32              (400 KB)
#define OFF_PS    0x280000   // 512*61*4 f32
#define OFF_PI    0x300000   // 512*61*4 i32
#define OFF_IDX   0x380000   // 2048 i32
#define OFF_CAND  0x3A0000   // 512*16 i32 candidates
#define OFF_KVT   0x400000   // keys transposed [2][256][1024] f32 (2 MB)
#define OFF_AO    0x600000   // attention out [2048][256] f32 (2 MB)
#define OFF_KVV   0x800000   // values dense [2][1024][256] f32 (2 MB)
#define OFF_DBK16 0xA00000   // bf16 db copy 100000*256*2 = 51.2 MB

typedef unsigned short ushort_t;
typedef unsigned int   uint_t;
typedef __attribute__((ext_vector_type(8)))  __bf16 bf16x8;
typedef __attribute__((ext_vector_type(16))) float  f32x16;

// sorted-insert of (score,idx) into descending top-4; ties -> lower index first
__device__ __forceinline__ void ins4(float sc, int n, float s[4], int id[4]) {
  if (sc > s[3] || (sc == s[3] && n < id[3])) {
    s[3] = sc; id[3] = n;
#pragma unroll
    for (int k = 3; k > 0; --k) {
      if (s[k] > s[k - 1] || (s[k] == s[k - 1] && id[k] < id[k - 1])) {
        float ts = s[k]; s[k] = s[k - 1]; s[k - 1] = ts;
        int ti = id[k]; id[k] = id[k - 1]; id[k - 1] = ti;
      }
    }
  }
}

__device__ __forceinline__ uint_t bfpack(float a, float b) {   // 2x fp32 -> packed bf16 (RNE)
  uint_t ua = __float_as_uint(a), ub = __float_as_uint(b);
  ua = (ua + 0x7fffu + ((ua >> 16) & 1u)) >> 16;
  ub = (ub + 0x7fffu + ((ub >> 16) & 1u)) >> 16;
  return ua | (ub << 16);
}

// ---------------- q = (hidden @ wq_in) @ wq_out,  one block per token ----------------
__global__ __launch_bounds__(256) void k_compute_q(
    const float* __restrict__ hidden, const float* __restrict__ wq_in,
    const float* __restrict__ wq_out, float* __restrict__ q) {
  __shared__ float hrow[H_];
  __shared__ float part[8][R_];
  __shared__ float q1[R_];
  const int m = blockIdx.x;
  const int t = threadIdx.x;
  const float* hp = hidden + (size_t)m * H_;
  ((float4*)hrow)[t]       = ((const float4*)hp)[t];
  ((float4*)hrow)[t + 256] = ((const float4*)hp)[t + 256];
  __syncthreads();
  const int r = t & 31, c = t >> 5;
  float p = 0.f;
#pragma unroll 4
  for (int e = c * 256; e < c * 256 + 256; ++e)
    p = fmaf(hrow[e], wq_in[(size_t)e * R_ + r], p);
  part[c][r] = p;
  __syncthreads();
  if (t < R_) {
    float s = 0.f;
#pragma unroll
    for (int cc = 0; cc < 8; ++cc) s += part[cc][t];
    q1[t] = s;
  }
  __syncthreads();
  float acc = 0.f;
#pragma unroll
  for (int rr = 0; rr < R_; ++rr) acc = fmaf(q1[rr], wq_out[rr * D_ + t], acc);
  q[(size_t)m * D_ + t] = acc;
}

// ---------------- kn[n] = |db_keys[n]|^2 (+ fused bf16 conversion) ----------------
__global__ __launch_bounds__(256) void k_kn_cvt(const float* __restrict__ dbk,
                                               float* __restrict__ kn,
                                               ushort_t* __restrict__ dbk16) {
  const int w = threadIdx.x >> 6, l = threadIdx.x & 63;
  const int n = blockIdx.x * 4 + w;
  if (n >= NDB_) return;
  const float4 v = ((const float4*)(dbk + (size_t)n * D_))[l];
  uint2 p; p.x = bfpack(v.x, v.y); p.y = bfpack(v.z, v.w);
  ((uint2*)(dbk16 + (size_t)n * D_))[l] = p;
  float s = v.x * v.x + v.y * v.y + v.z * v.z + v.w * v.w;
#pragma unroll
  for (int off = 32; off; off >>= 1) s += __shfl_down(s, off);
  if (l == 0) kn[n] = s;
}

// plain kn (fallback path, no bf16 copy)
__global__ __launch_bounds__(256) void k_kn(const float* __restrict__ dbk,
                                            float* __restrict__ kn) {
  const int w = threadIdx.x >> 6, l = threadIdx.x & 63;
  const int n = blockIdx.x * 4 + w;
  if (n >= NDB_) return;
  const float4 v = ((const float4*)(dbk + (size_t)n * D_))[l];
  float s = v.x * v.x + v.y * v.y + v.z * v.z + v.w * v.w;
#pragma unroll
  for (int off = 32; off; off >>= 1) s += __shfl_down(s, off);
  if (l == 0) kn[n] = s;
}

// ---------------- bf16 MFMA knn: per-(qb, chunk) partial top-4 ----------------
// approx score = 2*(q.k)_bf16 - kn_fp32 (verified: picks identical indices as fp32
// at this problem's top-16 margin; final top-4 from exact fp32 rescore anyway).
// Block: 64q x 128n, K=256 in two halves. A resident in LDS (XOR chunk swizzle);
// B via global_load_lds w=16 with swizzle folded into the GLOBAL address (LDS side
// lane-contiguous, m104 rule). Scores overlay B. 64 KB LDS -> 2 blocks/CU.
// Grid: x=qb (8, fastest) so the 8 blocks sharing a chunk are dispatch-adjacent.
__global__ __launch_bounds__(256, 2) void k_knn_mfma(
    const float* __restrict__ q, const ushort_t* __restrict__ dbk16,
    const float* __restrict__ kn, float* __restrict__ pscore,
    int* __restrict__ pidx) {
  __shared__ __align__(16) char smem[65536];
  ushort_t* sA = (ushort_t*)smem;            // 64 rows x 32 chunks x 16B = 32768
  ushort_t* sB = (ushort_t*)(smem + 32768);  // 128 rows x 16 chunks x 16B = 32768
  float*    sS = (float*)(smem + 32768);     // scores [64 m][128 n] overlay on B

  const int tid = threadIdx.x;
  const int wv = tid >> 6, ln = tid & 63;
  const int lm = ln & 31, lh = ln >> 5;
  const int tx = tid & 15, ty = tid >> 4;
  const int qb = blockIdx.x, chunk = blockIdx.y;
  const int row_base = chunk * CHUNK_ROWS;

  // ---- stage A once: 64 selected q rows -> bf16, swizzled chunks ----
  {
    const int m = tid & 63, cg = tid >> 6;
    const int sq = qb * MT + m;
    const float* qp = q + ((size_t)((sq >> 8) * S_ + (sq & 255))) * D_;
#pragma unroll
    for (int cc = 0; cc < 8; ++cc) {
      const int c = cg * 8 + cc;
      const float4 v0 = *(const float4*)(qp + c * 8);
      const float4 v1 = *(const float4*)(qp + c * 8 + 4);
      uint4 pk;
      pk.x = bfpack(v0.x, v0.y); pk.y = bfpack(v0.z, v0.w);
      pk.z = bfpack(v1.x, v1.y); pk.w = bfpack(v1.z, v1.w);
      *(uint4*)&sA[(m * 32 + (c ^ (m & 7))) * 8] = pk;
    }
  }

  float s4[4][4]; int i4[4][4];
#pragma unroll
  for (int a = 0; a < 4; ++a)
#pragma unroll
    for (int b = 0; b < 4; ++b) { s4[a][b] = NEG_INF; i4[a][b] = IDX_MAX; }

  for (int tile = 0; tile < TILES; ++tile) {
    const int row0 = row_base + tile * NT;
    if (row0 >= NDB_) break;

    f32x16 acc0, acc1;
#pragma unroll
    for (int r = 0; r < 16; ++r) { acc0[r] = 0.f; acc1[r] = 0.f; }

    for (int kh = 0; kh < 2; ++kh) {
      __syncthreads();    // prev consumers of sB/sS done
      // ---- stage B half: wave wv stages rows [wv*32, wv*32+32) ----
      {
        const int n_in = ln >> 4;          // row within 4-row instr group
        const int p    = ln & 15;          // stored chunk position
#pragma unroll
        for (int i = 0; i < 8; ++i) {
          const int nloc = wv * 32 + i * 4 + n_in;
          int krow = row0 + nloc; if (krow >= NDB_) krow = NDB_ - 1;
          const int c = p ^ (nloc & 7);    // global chunk within half
          const ushort_t* gp = dbk16 + (size_t)krow * D_ + (kh * 16 + c) * 8;
          ushort_t* lp = sB + (size_t)(wv * 32 + i * 4) * 128;  // wave-uniform base
          __builtin_amdgcn_global_load_lds(
              (const __attribute__((address_space(1))) void*)gp,
              (__attribute__((address_space(3))) void*)lp, 16, 0, 0);
        }
      }
      __syncthreads();
      // ---- MFMA over this k-half: 8 steps of K=16 ----
      const int nB = wv * 32 + lm;
      const int bswz = nB & 7;
#pragma unroll
      for (int ks = 0; ks < 8; ++ks) {
        const int cA = kh * 16 + ks * 2 + lh;
        const bf16x8 a0 = *(const bf16x8*)&sA[(lm * 32 + (cA ^ (lm & 7))) * 8];
        const bf16x8 a1 = *(const bf16x8*)&sA[((32 + lm) * 32 + (cA ^ (lm & 7))) * 8];
        const bf16x8 bb = *(const bf16x8*)&sB[(nB * 16 + ((ks * 2 + lh) ^ bswz)) * 8];
        acc0 = __builtin_amdgcn_mfma_f32_32x32x16_bf16(a0, bb, acc0, 0, 0, 0);
        acc1 = __builtin_amdgcn_mfma_f32_32x32x16_bf16(a1, bb, acc1, 0, 0, 0);
      }
    }
    __syncthreads();   // all B reads done -> safe to overlay scores

    // ---- write C frags to LDS: sS[m][n] (bank = n%32 = lane, conflict-free) ----
    {
      const int n = (tid >> 6) * 32 + lm;
#pragma unroll
      for (int r = 0; r < 16; ++r) {
        const int mrow = (r & 3) + 8 * (r >> 2) + 4 * lh;
        sS[mrow * 128 + n]        = acc0[r];
        sS[(32 + mrow) * 128 + n] = acc1[r];
      }
    }
    __syncthreads();

    // ---- prefiltered select: thread = 8 n cols x 4 q rows, running top-4 ----
    {
      const int nbase = row0 + tx * 8;
      float knv[8]; int nok[8];
#pragma unroll
      for (int j = 0; j < 8; ++j) {
        nok[j] = (nbase + j < NDB_);
        knv[j] = nok[j] ? kn[nbase + j] : 0.f;
      }
#pragma unroll
      for (int qi = 0; qi < 4; ++qi) {
        const int m = ty * 4 + qi;
        const float4 v0 = *(const float4*)&sS[m * 128 + tx * 8];
        const float4 v1 = *(const float4*)&sS[m * 128 + tx * 8 + 4];
        const float sv[8] = {v0.x, v0.y, v0.z, v0.w, v1.x, v1.y, v1.z, v1.w};
        float v[8];
#pragma unroll
        for (int j = 0; j < 8; ++j)
          v[j] = nok[j] ? fmaf(2.f, sv[j], -knv[j]) : NEG_INF;
        const float mx = fmaxf(fmaxf(fmaxf(v[0], v[1]), fmaxf(v[2], v[3])),
                               fmaxf(fmaxf(v[4], v[5]), fmaxf(v[6], v[7])));
        if (mx >= s4[qi][3]) {
#pragma unroll
          for (int j = 0; j < 8; ++j)
            if (nok[j]) ins4(v[j], nbase + j, s4[qi], i4[qi]);
        }
      }
    }
  }

  // ---- block merge: 64 cand-sets of 4 per query -> top-4 for (query, chunk) ----
  __syncthreads();
  float* cs = (float*)smem;
  int*   ci = (int*)(smem + 64 * 65 * 4);
#pragma unroll
  for (int qi = 0; qi < 4; ++qi)
#pragma unroll
    for (int k = 0; k < 4; ++k) {
      cs[(ty * 4 + qi) * 65 + tx * 4 + k] = s4[qi][k];
      ci[(ty * 4 + qi) * 65 + tx * 4 + k] = i4[qi][k];
    }
  __syncthreads();
  if (tid < 64) {
    float fs[4]; int fi[4];
#pragma unroll
    for (int k = 0; k < 4; ++k) { fs[k] = NEG_INF; fi[k] = IDX_MAX; }
    for (int c = 0; c < 64; ++c)
      ins4(cs[tid * 65 + c], ci[tid * 65 + c], fs, fi);
    const int sq = qb * MT + tid;
    float* po = pscore + ((size_t)sq * NCHUNK + chunk) * 4;
    int*   io = pidx   + ((size_t)sq * NCHUNK + chunk) * 4;
#pragma unroll
    for (int k = 0; k < 4; ++k) { po[k] = fs[k]; io[k] = fi[k]; }
  }
}

// ---------------- fp32 fallback knn (round-1 kernel, used if ws too small) ----------------
__global__ __launch_bounds__(256) void k_knn_partial(
    const float* __restrict__ q, const float* __restrict__ dbk,
    const float* __restrict__ kn, float* __restrict__ pscore,
    int* __restrict__ pidx) {
  __shared__ float smem[3 * KC * LSTR];
  float* sA  = smem;
  float* sB0 = smem + KC * LSTR;
  float* sB1 = smem + 2 * KC * LSTR;
  const int tid = threadIdx.x;
  const int tx = tid & 15, ty = tid >> 4;
  const int chunk = blockIdx.x, qb = blockIdx.y;
  const int arq = tid >> 2;
  const int aqd = (tid & 3) * 4;
  const int brk = tid >> 1;
  const int bh  = tid & 1;
  const int bcol = ((brk >> 3) << 2) | (brk & 3);
  float* sBw = (brk & 4) ? sB1 : sB0;
  const int sq_a = qb * MT + arq;
  const float* qsrc = q + ((size_t)((sq_a >> 8) * S_ + (sq_a & 255))) * D_;
  float s4[4][4]; int i4[4][4];
#pragma unroll
  for (int a = 0; a < 4; ++a)
#pragma unroll
    for (int b = 0; b < 4; ++b) { s4[a][b] = NEG_INF; i4[a][b] = IDX_MAX; }
  const int row_base = chunk * CHUNK_ROWS;
  for (int tile = 0; tile < TILES; ++tile) {
    const int row0 = row_base + tile * NT;
    if (row0 >= NDB_) break;
    int krow = row0 + brk; if (krow >= NDB_) krow = NDB_ - 1;
    const float* ksrc = dbk + (size_t)krow * D_;
    float acc[4][8];
#pragma unroll
    for (int a = 0; a < 4; ++a)
#pragma unroll
      for (int b = 0; b < 8; ++b) acc[a][b] = 0.f;
    for (int kc = 0; kc < 4; ++kc) {
      __syncthreads();
#pragma unroll
      for (int p = 0; p < 4; ++p) {
        const int kkl = p * 16 + aqd;
        const float4 v = *(const float4*)(qsrc + kc * KC + kkl);
        sA[(kkl + 0) * LSTR + arq] = v.x;
        sA[(kkl + 1) * LSTR + arq] = v.y;
        sA[(kkl + 2) * LSTR + arq] = v.z;
        sA[(kkl + 3) * LSTR + arq] = v.w;
      }
#pragma unroll
      for (int p = 0; p < 8; ++p) {
        const int kkl = bh * 32 + p * 4;
        const float4 v = *(const float4*)(ksrc + kc * KC + kkl);
        sBw[(kkl + 0) * LSTR + bcol] = v.x;
        sBw[(kkl + 1) * LSTR + bcol] = v.y;
        sBw[(kkl + 2) * LSTR + bcol] = v.z;
        sBw[(kkl + 3) * LSTR + bcol] = v.w;
      }
      __syncthreads();
#pragma unroll 4
      for (int kk = 0; kk < KC; ++kk) {
        const float4 a  = *(const float4*)&sA [kk * LSTR + ty * 4];
        const float4 b0 = *(const float4*)&sB0[kk * LSTR + tx * 4];
        const float4 b1 = *(const float4*)&sB1[kk * LSTR + tx * 4];
        const float av[4] = {a.x, a.y, a.z, a.w};
        const float bv[8] = {b0.x, b0.y, b0.z, b0.w, b1.x, b1.y, b1.z, b1.w};
#pragma unroll
        for (int qi = 0; qi < 4; ++qi)
#pragma unroll
          for (int nj = 0; nj < 8; ++nj)
            acc[qi][nj] = fmaf(av[qi], bv[nj], acc[qi][nj]);
      }
    }
#pragma unroll
    for (int nj = 0; nj < 8; ++nj) {
      const int n = row0 + tx * 8 + nj;
      if (n < NDB_) {
        const float knj = kn[n];
        ins4(2.f * acc[0][nj] - knj, n, s4[0], i4[0]);
        ins4(2.f * acc[1][nj] - knj, n, s4[1], i4[1]);
        ins4(2.f * acc[2][nj] - knj, n, s4[2], i4[2]);
        ins4(2.f * acc[3][nj] - knj, n, s4[3], i4[3]);
      }
    }
  }
  __syncthreads();
  float* cs = smem;
  int*   ci = (int*)(smem + 64 * 65);
#pragma unroll
  for (int qi = 0; qi < 4; ++qi)
#pragma unroll
    for (int k = 0; k < 4; ++k) {
      cs[(ty * 4 + qi) * 65 + tx * 4 + k] = s4[qi][k];
      ci[(ty * 4 + qi) * 65 + tx * 4 + k] = i4[qi][k];
    }
  __syncthreads();
  if (tid < 64) {
    float fs[4]; int fi[4];
#pragma unroll
    for (int k = 0; k < 4; ++k) { fs[k] = NEG_INF; fi[k] = IDX_MAX; }
    for (int c = 0; c < 64; ++c)
      ins4(cs[tid * 65 + c], ci[tid * 65 + c], fs, fi);
    const int sq = qb * MT + tid;
    float* po = pscore + ((size_t)sq * NCHUNK + chunk) * 4;
    int*   io = pidx   + ((size_t)sq * NCHUNK + chunk) * 4;
#pragma unroll
    for (int k = 0; k < 4; ++k) { po[k] = fs[k]; io[k] = fi[k]; }
  }
}

// ---------------- merge chunk candidates -> sorted global top-R ----------------
template <int RANKS>
__device__ __forceinline__ void merge_top(const float* __restrict__ pscore,
                                          const int* __restrict__ pidx,
                                          int* __restrict__ outp) {
  const int sq = blockIdx.x, l = threadIdx.x;
  float s4[4]; int i4[4];
#pragma unroll
  for (int k = 0; k < 4; ++k) { s4[k] = NEG_INF; i4[k] = IDX_MAX; }
  for (int c = l; c < NCHUNK * 4; c += 64)
    ins4(pscore[(size_t)sq * NCHUNK * 4 + c], pidx[(size_t)sq * NCHUNK * 4 + c], s4, i4);
#pragma unroll
  for (int r = 0; r < RANKS; ++r) {
    float s = s4[0]; int i = i4[0];
#pragma unroll
    for (int off = 32; off; off >>= 1) {
      float so = __shfl_down(s, off); int io = __shfl_down(i, off);
      if (so > s || (so == s && io < i)) { s = so; i = io; }
    }
    const float sw = __shfl(s, 0); const int iw = __shfl(i, 0);
    if (l == 0) outp[sq * RANKS + r] = iw;
    if (s4[0] == sw && i4[0] == iw) {
      s4[0] = s4[1]; i4[0] = i4[1];
      s4[1] = s4[2]; i4[1] = i4[2];
      s4[2] = s4[3]; i4[2] = i4[3];
      s4[3] = NEG_INF; i4[3] = IDX_MAX;
    }
  }
}

__global__ __launch_bounds__(64) void k_knn_merge4(const float* __restrict__ ps,
                                                   const int* __restrict__ pi,
                                                   int* __restrict__ knn_idx) {
  merge_top<4>(ps, pi, knn_idx);
}
__global__ __launch_bounds__(64) void k_knn_merge16(const float* __restrict__ ps,
                                                    const int* __restrict__ pi,
                                                    int* __restrict__ cand) {
  merge_top<16>(ps, pi, cand);
}

// ---------------- exact fp32 rescore of 16 candidates -> final sorted top-4 ----------------
__global__ __launch_bounds__(256) void k_rescore(const float* __restrict__ q,
                                                 const float* __restrict__ dbk,
                                                 const float* __restrict__ kn,
                                                 const int* __restrict__ cand,
                                                 int* __restrict__ knn_idx) {
  __shared__ float scs[16];
  __shared__ int   sci[16];
  const int sq = blockIdx.x, wv = threadIdx.x >> 6, l = threadIdx.x & 63;
  const float* qp = q + ((size_t)((sq >> 8) * S_ + (sq & 255))) * D_;
  const float4 qv = ((const float4*)qp)[l];
  for (int cc = wv; cc < 16; cc += 4) {
    const int n = cand[sq * 16 + cc];
    const float4 kv = ((const float4*)(dbk + (size_t)n * D_))[l];
    float s = qv.x * kv.x + qv.y * kv.y + qv.z * kv.z + qv.w * kv.w;
#pragma unroll
    for (int off = 32; off; off >>= 1) s += __shfl_down(s, off);
    if (l == 0) { scs[cc] = 2.f * s - kn[n]; sci[cc] = n; }
  }
  __syncthreads();
  if (threadIdx.x == 0) {
    float s4[4]; int i4[4];
#pragma unroll
    for (int k = 0; k < 4; ++k) { s4[k] = NEG_INF; i4[k] = IDX_MAX; }
#pragma unroll
    for (int c = 0; c < 16; ++c) ins4(scs[c], sci[c], s4, i4);
#pragma unroll
    for (int k = 0; k < 4; ++k) knn_idx[sq * 4 + k] = i4[k];
  }
}

// -------- gather: keys transposed kvT[b][d][j] + values dense kvV[b][j][d] --------
__global__ __launch_bounds__(256) void k_gather(const float* __restrict__ dbk,
                                                const float* __restrict__ dbv,
                                                const int* __restrict__ knn_idx,
                                                float* __restrict__ kvT,
                                                float* __restrict__ kvV) {
  const int b = blockIdx.x >> 6, j0 = (blockIdx.x & 63) * 16;
  const int w = threadIdx.x >> 6, l = threadIdx.x & 63;
  float* dstT = kvT + (size_t)b * D_ * 1024;
  float* dstV = kvV + (size_t)b * 1024 * D_;
  for (int jj = w; jj < 16; jj += 4) {
    const int j = j0 + jj;
    const int row = knn_idx[b * 1024 + j];
    const float4 kv = ((const float4*)(dbk + (size_t)row * D_))[l];
    dstT[(4 * l + 0) * 1024 + j] = kv.x;
    dstT[(4 * l + 1) * 1024 + j] = kv.y;
    dstT[(4 * l + 2) * 1024 + j] = kv.z;
    dstT[(4 * l + 3) * 1024 + j] = kv.w;
    const float4 vv = ((const float4*)(dbv + (size_t)row * D_))[l];
    ((float4*)(dstV + (size_t)j * D_))[l] = vv;
  }
}

// ---------------- attention: one block per (b, i) ----------------
__global__ __launch_bounds__(256) void k_attn(const float* __restrict__ qarr,
                                              const float* __restrict__ kvT,
                                              const float* __restrict__ kvV,
                                              float* __restrict__ attout) {
  __shared__ float qrow[D_];
  __shared__ float attw[1024];
  __shared__ float red1[4], red2[4];
  const int b = blockIdx.x >> 10, i = blockIdx.x & 1023;
  const int t = threadIdx.x;
  const int nk = i + 1;
  qrow[t] = qarr[((size_t)b * S_ + i) * D_ + t];
  __syncthreads();
  const int cmax = (nk + 255) >> 8;
  const float scale = 0.0625f;
  float sc[4]; float mloc = NEG_INF;
#pragma unroll
  for (int c = 0; c < 4; ++c) {
    sc[c] = NEG_INF;
    if (c < cmax) {
      const int j = c * 256 + t;
      float a = 0.f;
      const float* kp = kvT + (size_t)b * D_ * 1024 + j;
#pragma unroll 8
      for (int d = 0; d < D_; ++d) a = fmaf(qrow[d], kp[(size_t)d * 1024], a);
      if (j < nk) sc[c] = a * scale;
    }
    mloc = fmaxf(mloc, sc[c]);
  }
#pragma unroll
  for (int off = 32; off; off >>= 1) mloc = fmaxf(mloc, __shfl_down(mloc, off));
  if ((t & 63) == 0) red1[t >> 6] = mloc;
  __syncthreads();
  const float mmax = fmaxf(fmaxf(red1[0], red1[1]), fmaxf(red1[2], red1[3]));
  float sloc = 0.f; float pv[4];
#pragma unroll
  for (int c = 0; c < 4; ++c) {
    pv[c] = (sc[c] > NEG_INF * 0.5f) ? __expf(sc[c] - mmax) : 0.f;
    sloc += pv[c];
  }
#pragma unroll
  for (int off = 32; off; off >>= 1) sloc += __shfl_down(sloc, off);
  if ((t & 63) == 0) red2[t >> 6] = sloc;
  __syncthreads();
  const float inv = 1.f / (red2[0] + red2[1] + red2[2] + red2[3]);
#pragma unroll
  for (int c = 0; c < 4; ++c)
    if (c < cmax) attw[c * 256 + t] = pv[c] * inv;
  __syncthreads();
  // PV from dense gathered values: sequential rows, coalesced lanes
  const float* vb = kvV + (size_t)b * 1024 * D_;
  float a0 = 0.f, a1 = 0.f, a2 = 0.f, a3 = 0.f;
  int j = 0;
  for (; j + 4 <= nk; j += 4) {
    a0 = fmaf(attw[j + 0], vb[(size_t)(j + 0) * D_ + t], a0);
    a1 = fmaf(attw[j + 1], vb[(size_t)(j + 1) * D_ + t], a1);
    a2 = fmaf(attw[j + 2], vb[(size_t)(j + 2) * D_ + t], a2);
    a3 = fmaf(attw[j + 3], vb[(size_t)(j + 3) * D_ + t], a3);
  }
  for (; j < nk; ++j) a0 = fmaf(attw[j], vb[(size_t)j * D_ + t], a0);
  attout[((size_t)b * S_ + i) * D_ + t] = (a0 + a1) + (a2 + a3);
}

// ---------------- y = (attout @ wv_in) @ wv_out, one block per token ----------------
__global__ __launch_bounds__(256) void k_out(const float* __restrict__ attout,
                                             const float* __restrict__ wv_in,
                                             const float* __restrict__ wv_out,
                                             float* __restrict__ y) {
  __shared__ float row[D_];
  __shared__ float part[8][R_];
  __shared__ float t32[R_];
  const int m = blockIdx.x, t = threadIdx.x;
  row[t] = attout[(size_t)m * D_ + t];
  __syncthreads();
  const int r = t & 31, c = t >> 5;
  float p = 0.f;
#pragma unroll
  for (int d = c * 32; d < c * 32 + 32; ++d)
    p = fmaf(row[d], wv_in[d * R_ + r], p);
  part[c][r] = p;
  __syncthreads();
  if (t < R_) {
    float s = 0.f;
#pragma unroll
    for (int cc = 0; cc < 8; ++cc) s += part[cc][t];
    t32[t] = s;
  }
  __syncthreads();
  for (int hh = t; hh < H_; hh += 256) {
    float a = 0.f;
#pragma unroll
    for (int rr = 0; rr < R_; ++rr) a = fmaf(t32[rr], wv_out[rr * H_ + hh], a);
    y[(size_t)m * H_ + hh] = a;
  }
}

extern "C" void kernel_launch(void* const* d_in, const int* in_sizes, int n_in,
                              void* d_out, int out_size, void* d_ws, size_t ws_size,
                              hipStream_t stream) {
  const float* hidden  = (const float*)d_in[0];
  const float* db_keys = (const float*)d_in[1];
  const float* db_vals = (const float*)d_in[2];
  const float* wq_in   = (const float*)d_in[3];
  const float* wq_out  = (const float*)d_in[4];
  const float* wv_in   = (const float*)d_in[5];
  const float* wv_out  = (const float*)d_in[6];
  float* out = (float*)d_out;

  char* ws = (char*)d_ws;
  float*    q      = (float*)(ws + OFF_Q);
  float*    kn     = (float*)(ws + OFF_KN);
  float*    ps     = (float*)(ws + OFF_PS);
  int*      pi     = (int*)  (ws + OFF_PI);
  int*      idx    = (int*)  (ws + OFF_IDX);
  int*      cand   = (int*)  (ws + OFF_CAND);
  float*    kvT    = (float*)(ws + OFF_KVT);
  float*    attout = (float*)(ws + OFF_AO);
  float*    kvV    = (float*)(ws + OFF_KVV);
  ushort_t* dbk16  = (ushort_t*)(ws + OFF_DBK16);

  const size_t need = (size_t)OFF_DBK16 + (size_t)NDB_ * D_ * 2;

  k_compute_q<<<B_ * S_, 256, 0, stream>>>(hidden, wq_in, wq_out, q);
  if (ws_size >= need) {
    // bf16 MFMA candidate path + exact fp32 rescore
    k_kn_cvt<<<(NDB_ + 3) / 4, 256, 0, stream>>>(db_keys, kn, dbk16);
    k_knn_mfma<<<dim3(8, NCHUNK), 256, 0, stream>>>(q, dbk16, kn, ps, pi);
    k_knn_merge16<<<NSEL, 64, 0, stream>>>(ps, pi, cand);
    k_rescore<<<NSEL, 256, 0, stream>>>(q, db_keys, kn, cand, idx);
  } else {
    // fp32 fallback
    k_kn<<<(NDB_ + 3) / 4, 256, 0, stream>>>(db_keys, kn);
    k_knn_partial<<<dim3(NCHUNK, 8), 256, 0, stream>>>(q, db_keys, kn, ps, pi);
    k_knn_merge4<<<NSEL, 64, 0, stream>>>(ps, pi, idx);
  }
  k_gather<<<2 * 64, 256, 0, stream>>>(db_keys, db_vals, idx, kvT, kvV);
  k_attn<<<B_ * S_, 256, 0, stream>>>(q, kvT, kvV, attout);
  k_out<<<B_ * S_, 256, 0, stream>>>(attout, wv_in, wv_out, out);
}